// Round 4
// baseline (59.166 us; speedup 1.0000x reference)
//
#include <hip/hip_runtime.h>
#include <math.h>

// Problem constants (match reference): B=8, N=256, MAX_DIM=2, D=4
#define PB 8
#define PN 256
#define PD 4
#define PEPS 1e-8f
#define FLAG_MAGIC 0x5CA1AB1Eu

// Single-node design: 16 blocks x 64 threads. Block = one wave = one
// (dim, b) task. Each wave register-sorts both 256-element projection
// arrays (layout idx = lane*4 + r: j=1,2 bitonic passes are in-lane VALU,
// j>=4 passes are __shfl_xor with mask j>>2 -> 21 cross-lane passes).
// Each block publishes its partial via {value, MAGIC-flag} agent-scope
// atomics; block 0 spin-acquires the 15 peer flags (all 16 blocks are
// co-resident on 256 CUs -> no deadlock), reduces, writes the scalar.
// The MAGIC handshake is correct for ANY initial d_ws contents (harness
// re-poisons to 0xAA before every timed launch).
//
// Validity of sorting: Hungarian assignment on |a_i - b_j| over scalars is
// minimized by sorted-order matching; the reference consumes only the total
// cost, and the [B:2B) concat half is the mirrored matching (factor 2).

__device__ __forceinline__ void cswap(float& a, float& b, bool up) {
    float mn = fminf(a, b);
    float mx = fmaxf(a, b);
    a = up ? mn : mx;
    b = up ? mx : mn;
}

// One cross-lane bitonic pass (shuffle mask m) applied to both arrays.
__device__ __forceinline__ void xpass(float (&p)[4], float (&q)[4],
                                      int m, bool keepmin) {
    #pragma unroll
    for (int r = 0; r < 4; ++r) {
        float po = __shfl_xor(p[r], m, 64);
        float qo = __shfl_xor(q[r], m, 64);
        float pmn = fminf(p[r], po), pmx = fmaxf(p[r], po);
        float qmn = fminf(q[r], qo), qmx = fmaxf(q[r], qo);
        p[r] = keepmin ? pmn : pmx;
        q[r] = keepmin ? qmn : qmx;
    }
}

// In-lane j=2 then j=1 passes, direction `up`, both arrays.
__device__ __forceinline__ void lpass(float (&p)[4], float (&q)[4], bool up) {
    cswap(p[0], p[2], up); cswap(p[1], p[3], up);
    cswap(q[0], q[2], up); cswap(q[1], q[3], up);
    cswap(p[0], p[1], up); cswap(p[2], p[3], up);
    cswap(q[0], q[1], up); cswap(q[2], q[3], up);
}

__global__ __launch_bounds__(64) void hung_kernel(
    const float* __restrict__ set1,   // [B, N, D] fp32
    const float* __restrict__ set2,   // [B, N, D] fp32
    float* __restrict__ out,          // [1] fp32
    unsigned* __restrict__ ws)        // ws[0..15] value bits, ws[16..31] flags
{
    const int blk  = blockIdx.x;      // 0..15
    const int dim  = blk >> 3;        // 0 or 1
    const int b    = blk & 7;         // 0..7
    const int lane = threadIdx.x;     // 0..63 (one wave)
    const float fdim = (float)dim;

    // ---- load 4 consecutive points per lane, compute masked projections ----
    float p[4];   // set1 projections, element idx = lane*4 + r
    float q[4];   // set2 projections
    const float4* s1v = (const float4*)(set1 + (size_t)b * PN * PD);
    const float4* s2v = (const float4*)(set2 + (size_t)b * PN * PD);
    #pragma unroll
    for (int r = 0; r < 4; ++r) {
        int n = lane * 4 + r;
        float4 e1 = s1v[n];
        float4 e2 = s2v[n];
        bool m1 = (e1.z == fdim);              // set1: float label == dim
        int lab2 = (e2.w > e2.z) ? 1 : 0;      // set2: argmax, first-idx ties
        bool m2 = (lab2 == dim);
        float mx1 = m1 ? e1.x : 0.0f, my1 = m1 ? e1.y : 0.0f;
        float mx2 = m2 ? e2.x : 0.0f, my2 = m2 ? e2.y : 0.0f;
        // projection x + sqrt(y+eps)/2 (y zeroed by the ref's aliasing)
        p[r] = mx1 + sqrtf(my1 + PEPS) * 0.5f;
        q[r] = mx2 + sqrtf(my2 + PEPS) * 0.5f;
    }

    // ---- bitonic sort 256 elems (idx = lane*4 + r), ascending ----
    // k = 2: j=1 in-lane; pair (0,1) up, (2,3) down
    cswap(p[0], p[1], true);  cswap(p[2], p[3], false);
    cswap(q[0], q[1], true);  cswap(q[2], q[3], false);
    // k = 4: j=2,1 in-lane; up = ((idx&4)==0) = ((lane&1)==0)
    lpass(p, q, (lane & 1) == 0);
    // k = 8 .. 256
    #pragma unroll
    for (int k = 8; k <= 256; k <<= 1) {
        // up = ((idx & k) == 0); idx bit log2(k) is lane bit log2(k)-2
        bool up = (k == 256) ? true : ((lane & (k >> 2)) == 0);
        #pragma unroll
        for (int m = k >> 3; m >= 1; m >>= 1) {   // j = k/2 .. 4, m = j>>2
            bool lower = ((lane & m) == 0);        // (idx & j) == 0
            xpass(p, q, m, up == lower);
        }
        lpass(p, q, up);                           // j = 2, 1
    }

    // ---- per-lane matched cost, wave butterfly (total lands in ALL lanes) --
    float v = fabsf(p[0] - q[0]) + fabsf(p[1] - q[1])
            + fabsf(p[2] - q[2]) + fabsf(p[3] - q[3]);
    #pragma unroll
    for (int off = 32; off > 0; off >>= 1)
        v += __shfl_xor(v, off, 64);

    // ---- publish partial: value (relaxed) then flag (release) ----
    if (lane == 0) {
        __hip_atomic_store(&ws[blk], __float_as_uint(v),
                           __ATOMIC_RELAXED, __HIP_MEMORY_SCOPE_AGENT);
        __hip_atomic_store(&ws[16 + blk], FLAG_MAGIC,
                           __ATOMIC_RELEASE, __HIP_MEMORY_SCOPE_AGENT);
    }

    // ---- block 0 aggregates: lanes 1..15 spin on peer flags ----
    if (blk == 0) {
        float t;
        if (lane == 0) {
            t = v;                                 // own partial
        } else if (lane < 16) {
            while (__hip_atomic_load(&ws[16 + lane], __ATOMIC_ACQUIRE,
                                     __HIP_MEMORY_SCOPE_AGENT) != FLAG_MAGIC) {}
            t = __uint_as_float(__hip_atomic_load(&ws[lane], __ATOMIC_RELAXED,
                                                  __HIP_MEMORY_SCOPE_AGENT));
        } else {
            t = 0.0f;
        }
        #pragma unroll
        for (int off = 8; off > 0; off >>= 1)
            t += __shfl_xor(t, off, 16);           // reduce lanes 0..15
        if (lane == 0)
            out[0] = t * (2.0f / (float)PN);       // x2 concat symmetry, /N mean
    }
}

extern "C" void kernel_launch(void* const* d_in, const int* in_sizes, int n_in,
                              void* d_out, int out_size, void* d_ws, size_t ws_size,
                              hipStream_t stream) {
    const float* set1 = (const float*)d_in[0];   // [B,N,D] fp32
    const float* set2 = (const float*)d_in[1];   // [B,N,D] fp32
    float* out = (float*)d_out;                  // 1 float
    unsigned* ws = (unsigned*)d_ws;              // 32 u32 scratch

    hung_kernel<<<16, 64, 0, stream>>>(set1, set2, out, ws);
}